// Round 5
// baseline (304.635 us; speedup 1.0000x reference)
//
#include <hip/hip_runtime.h>
#include <float.h>
#include <stdint.h>

// SOM2D argmin ||x-w||^2 via split-f16 MFMA. N=32768, M=4096, D=128.
//
// score = ||w||^2 - 2 x.w  (||x||^2 constant per sample: dropped)
// cross = xh*wh + xl*wh + xh*wl  (f16 hi/lo split, fp32 accum; |err|~2e-5)
//
// Round-11: 32x32x16 MFMA. Rounds 8/9/10 (prefetch walls, acc dbuf, B-in-LDS)
// all lost to round-6's compiler-scheduled register-B structure (96us,
// MfmaUtil 47.7%): at 16x16 the live set (~220) allows only 2 waves/SIMD,
// too few to cover the distributed stalls. The 32x32x16 shape fixes the
// ECONOMICS: wave = 32 samples x 64 units/tile -> Ah 32 regs (was 64),
// Al-LDS 8KB/wave (32KB/block), acc 2xf32x16 = 32, best 32 (n-pair combined
// before compare). Liveness ~150 -> fits launch_bounds(256,3)'s 170-reg
// budget with margin -> 3 waves/SIMD (r7/r9 failed this at ~220 live).
// UG=3 -> 768 blocks = 3 blocks/CU. 48 MFMA/tile (was 96), 32x32 ubench
// rate +15%. Passes fused in one 8-step k-loop: B granules (bh0,bh1,bl0,
// bl1) die per-step -> minimal B liveness, compiler pipelines freely.
// wsq loaded at tile top, used ~1.6k cyc later at score (latency hidden).
// Layouts (documented mirrors of the verified 16x16 ones):
//   A: row=lane&31, k=(lane>>5)*8+j   B: col=lane&31, k=(lane>>5)*8+j
//   C: col=lane&31, row=(reg&3)+8*(reg>>2)+4*(lane>>5)  [m74/m101]
// Fused atomicMin finalize kept (verified r7-r10).

constexpr int D = 128;

typedef _Float16 f16x8  __attribute__((ext_vector_type(8)));
typedef float    f32x16 __attribute__((ext_vector_type(16)));

__device__ __forceinline__ void cvt_split(const float4& a0, const float4& a1,
                                          f16x8& h, f16x8& l) {
    float v[8] = {a0.x, a0.y, a0.z, a0.w, a1.x, a1.y, a1.z, a1.w};
#pragma unroll
    for (int j = 0; j < 8; ++j) {
        _Float16 hh = (_Float16)v[j];
        h[j] = hh;
        l[j] = (_Float16)(v[j] - (float)hh);
    }
}

// W (M x D fp32) -> frag-major hi/lo f16 + wsq, 64-unit tiles.
// Thread = (unit u, k-octet o). For mfma_32x32x16: tile T=u>>6, n-tile
// n=(u>>5)&1, col=u&31, k-step s=o>>1, half hh=o&1 (hh = lane>>5 at read).
//   slot = T*1024 + (2s+n)*64 + hh*32 + col
// Main-loop read for (s,n): hG[T*1024 + (2s+n)*64 + lane]. 1KB granules.
// Also inits keys (u64 max) and per-sample-group completion counters.
__global__ __launch_bounds__(256) void prep_kernel(
        const float* __restrict__ w, f16x8* __restrict__ hG,
        f16x8* __restrict__ lG, float* __restrict__ wsq, int M,
        unsigned long long* __restrict__ keys, unsigned* __restrict__ cnt,
        int N, int nGroups) {
    int g = blockIdx.x * 256 + threadIdx.x;
    if (keys && g < N) keys[g] = ~0ull;
    if (cnt && g < nGroups) cnt[g] = 0u;
    if (g >= M * 16) return;
    int u = g >> 4, o = g & 15;
    const float4* wp = reinterpret_cast<const float4*>(w + (size_t)u * D + o * 8);
    float4 a0 = wp[0], a1 = wp[1];
    f16x8 h, l;
    cvt_split(a0, a1, h, l);
    float ss = 0.f;
    ss = fmaf(a0.x, a0.x, ss); ss = fmaf(a0.y, a0.y, ss);
    ss = fmaf(a0.z, a0.z, ss); ss = fmaf(a0.w, a0.w, ss);
    ss = fmaf(a1.x, a1.x, ss); ss = fmaf(a1.y, a1.y, ss);
    ss = fmaf(a1.z, a1.z, ss); ss = fmaf(a1.w, a1.w, ss);
#pragma unroll
    for (int m = 1; m < 16; m <<= 1) ss += __shfl_xor(ss, m, 64);
    if (o == 0) wsq[u] = ss;
    int slot = ((u >> 6) << 10) + (((o >> 1) * 2 + ((u >> 5) & 1)) << 6)
             + ((o & 1) << 5) + (u & 31);
    hG[slot] = h;
    lG[slot] = l;
}

template <bool PARTIAL>
__global__ __launch_bounds__(256, 3) void som_main(
        const float* __restrict__ x, const f16x8* __restrict__ hG,
        const f16x8* __restrict__ lG, const float* __restrict__ wsq,
        const int* __restrict__ grid, int* __restrict__ out,
        unsigned long long* __restrict__ keys, unsigned* __restrict__ cnt,
        int unitGroups, int tilesQ, int tilesR, int N) {
    // Al (x-lo A-frags), wave-private: wave wv owns albuf[wv*512 .. +512).
    __shared__ f16x8 albuf[4 * 512];    // 32 KB -> 3 blocks/CU fits easily

    const int tid  = threadIdx.x;
    const int lane = tid & 63;
    const int wv   = tid >> 6;
    const int c32  = lane & 31;   // unit col-class / sample row
    const int h    = lane >> 5;   // k-half / row-half

    const int ug    = blockIdx.x % unitGroups;
    const int sg    = blockIdx.x / unitGroups;
    const int sWave = sg * 128 + wv * 32;   // this wave's 32 samples

    f16x8* myAl = &albuf[wv * 512];

    // ---- A-frags: 32 samples x K=128. Ah resident (32 VGPRs); Al -> LDS.
    // A[row = c32][k = 16s + h*8 + j], k-step s in 0..7.
    f16x8 Ah[8];
    {
        const float* xr = x + (size_t)(sWave + c32) * D + h * 8;
#pragma unroll
        for (int s = 0; s < 8; ++s) {
            float4 a0 = *reinterpret_cast<const float4*>(xr + 16 * s);
            float4 a1 = *reinterpret_cast<const float4*>(xr + 16 * s + 4);
            f16x8 hh, ll;
            cvt_split(a0, a1, hh, ll);
            Ah[s] = hh;
            myAl[s * 64 + lane] = ll;   // own slice only: no barrier needed
        }
    }

    float bestD[16];
    int   bestI[16];
#pragma unroll
    for (int r = 0; r < 16; ++r) { bestD[r] = FLT_MAX; bestI[r] = 0; }

    const int tile0  = ug * tilesQ + (ug < tilesR ? ug : tilesR);
    const int tcount = tilesQ + (ug < tilesR ? 1 : 0);

    for (int tt = 0; tt < tcount; ++tt) {
        const int tile  = tile0 + tt;
        const int uTile = tile * 64;
        const f16x8* hp = hG + ((size_t)tile << 10) + lane;
        const f16x8* lp = lG + ((size_t)tile << 10) + lane;

        // wsq loaded here, consumed ~1.6k cyc later at score: latency hidden.
        const float wq0 = wsq[uTile + c32];
        const float wq1 = wsq[uTile + 32 + c32];

        f32x16 acc0 = {}, acc1 = {};

        // fused 3-pass k-loop: per s, B granules (bh0,bh1,bl0,bl1) die at
        // the end of the step -> minimal B liveness, compiler pipelines.
#pragma unroll
        for (int s = 0; s < 8; ++s) {
            f16x8 bh0 = hp[s * 128];
            f16x8 bh1 = hp[s * 128 + 64];
            f16x8 bl0 = lp[s * 128];
            f16x8 bl1 = lp[s * 128 + 64];
            f16x8 al  = myAl[s * 64 + lane];
            acc0 = __builtin_amdgcn_mfma_f32_32x32x16_f16(Ah[s], bh0, acc0, 0, 0, 0);
            acc1 = __builtin_amdgcn_mfma_f32_32x32x16_f16(Ah[s], bh1, acc1, 0, 0, 0);
            acc0 = __builtin_amdgcn_mfma_f32_32x32x16_f16(al,    bh0, acc0, 0, 0, 0);
            acc1 = __builtin_amdgcn_mfma_f32_32x32x16_f16(al,    bh1, acc1, 0, 0, 0);
            acc0 = __builtin_amdgcn_mfma_f32_32x32x16_f16(Ah[s], bl0, acc0, 0, 0, 0);
            acc1 = __builtin_amdgcn_mfma_f32_32x32x16_f16(Ah[s], bl1, acc1, 0, 0, 0);
        }

        // ---- score + per-lane argmin.
        // C: col=lane&31, row=(r&3)+8*(r>>2)+4*h. n-pair combined first
        // (strict < keeps n=0, the lower unit, on ties).
        const int i0 = uTile + c32;
        const int i1 = uTile + 32 + c32;
#pragma unroll
        for (int r = 0; r < 16; ++r) {
            float v0 = fmaf(-2.f, acc0[r], wq0);
            float v1 = fmaf(-2.f, acc1[r], wq1);
            bool  sel = v1 < v0;
            float v   = sel ? v1 : v0;
            int   id  = sel ? i1 : i0;
            if (v < bestD[r]) { bestD[r] = v; bestI[r] = id; }  // earlier tile wins ties
        }
    }

    // ---- reduce over the 32 col-classes (xor within each 32-lane half) ----
#pragma unroll
    for (int r = 0; r < 16; ++r) {
        float d   = bestD[r];
        int   idx = bestI[r];
#pragma unroll
        for (int m = 1; m < 32; m <<= 1) {
            float od = __shfl_xor(d, m, 64);
            int   oi = __shfl_xor(idx, m, 64);
            if (od < d || (od == d && oi < idx)) { d = od; idx = oi; }
        }
        if (c32 == 0) {   // lanes 0 and 32 write their half's sample
            const int sOut = sWave + (r & 3) + 8 * (r >> 2) + 4 * h;
            if (PARTIAL) {
                unsigned ub = __float_as_uint(d);
                ub = (ub & 0x80000000u) ? ~ub : (ub | 0x80000000u);  // monotone map
                unsigned long long key = ((unsigned long long)ub << 32) | (unsigned)idx;
                atomicMin(&keys[sOut], key);
            } else {
                out[2 * sOut]     = grid[2 * idx];
                out[2 * sOut + 1] = grid[2 * idx + 1];
            }
        }
    }

    if (PARTIAL) {
        // Per-wave completion protocol (verified r10): last of the
        // 4*unitGroups waves for this sample group writes the output.
        __threadfence();
        int old = 0;
        if (lane == 0) old = (int)atomicAdd(&cnt[sg], 1u);
        old = __shfl(old, 0, 64);
        if (old == 4 * unitGroups - 1) {
            __threadfence();
#pragma unroll
            for (int j = 0; j < 2; ++j) {
                const int s0 = sg * 128 + j * 64 + lane;
                unsigned long long k = atomicMin(&keys[s0], ~0ull);  // atomic read
                int idx = (int)(unsigned)(k & 0xFFFFFFFFull);
                out[2 * s0]     = grid[2 * idx];
                out[2 * s0 + 1] = grid[2 * idx + 1];
            }
        }
    }
}

extern "C" void kernel_launch(void* const* d_in, const int* in_sizes, int n_in,
                              void* d_out, int out_size, void* d_ws, size_t ws_size,
                              hipStream_t stream) {
    const float* x    = (const float*)d_in[0];
    const float* w    = (const float*)d_in[1];
    const int*   grid = (const int*)d_in[2];
    int* out = (int*)d_out;

    const int N = in_sizes[0] / D;   // 32768
    const int M = in_sizes[1] / D;   // 4096

    // ws layout: hG (1 MB) | lG (1 MB) | wsq (16 KB) | keys (N*8) | cnt
    const size_t hlBytes   = (size_t)M * D * 2;
    const size_t baseBytes = 2 * hlBytes + (size_t)M * 4;
    const int sampleGroups = N / 128;   // blocks of 4 waves x 32 samples
    const size_t needBytes = baseBytes + (size_t)N * 8 + (size_t)sampleGroups * 4;

    f16x8* hG  = (f16x8*)d_ws;
    f16x8* lG  = (f16x8*)((char*)d_ws + hlBytes);
    float* wsq = (float*)((char*)d_ws + 2 * hlBytes);
    unsigned long long* keys = (unsigned long long*)((char*)d_ws + baseBytes);
    unsigned* cnt = (unsigned*)((char*)d_ws + baseBytes + (size_t)N * 8);

    const int tiles = M / 64;           // 64 tiles of 64 units
    const int UG = (ws_size >= needBytes) ? 3 : 1;   // 768 blocks = 3/CU

    prep_kernel<<<(M * 16 + 255) / 256, 256, 0, stream>>>(
        w, hG, lG, wsq, M,
        UG > 1 ? keys : nullptr, UG > 1 ? cnt : nullptr, N, sampleGroups);

    const int tq = tiles / UG, trm = tiles % UG;
    if (UG > 1) {
        som_main<true><<<sampleGroups * UG, 256, 0, stream>>>(
            x, hG, lG, wsq, grid, out, keys, cnt, UG, tq, trm, N);
    } else {
        som_main<false><<<sampleGroups, 256, 0, stream>>>(
            x, hG, lG, wsq, grid, out, nullptr, nullptr, 1, tiles, 0, N);
    }
}

// Round 6
// 224.184 us; speedup vs baseline: 1.3589x; 1.3589x over previous
//
#include <hip/hip_runtime.h>
#include <float.h>
#include <stdint.h>

// SOM2D argmin ||x-w||^2 via split-f16 MFMA. N=32768, M=4096, D=128.
//
// score = ||w||^2 - 2 x.w  (||x||^2 constant per sample: dropped)
// cross = xh*wh + xl*wh + xh*wl  (f16 hi/lo split, fp32 accum; |err|~2e-5)
//
// Round-12: round-6's som_main (the only structure the scheduler handles
// well: 48% MfmaUtil, VGPR 116, B reused across passes 1->2 so loads batch)
// with ONE resource change: Al k-step 3 moves to regs (Al3, +16 VGPR), LDS
// 64->48KB. Occupancy was LDS-bound (2 blocks/CU), NOT VGPR-bound: at
// 48KB and ~132 VGPR (<=170) the HW fits 3 blocks/CU = 3 waves/SIMD with
// bounds(256,2) unchanged -- no allocator cap (r7's mistake), no B hoist
// (r7/r9's spill), no fused k-loop (r11's JIT-load stall), no B-in-LDS
// barriers (r10). UG=6 -> 768 blocks so 3/CU is actually occupied; the 3
// same-SIMD waves come from different blocks (different tiles, no shared
// barriers) -> de-correlated streams cover each other's B-load waits and
// score tails. Fused atomicMin finalize kept (verified r7-r11); keys/cnt
// init in prep.

constexpr int D = 128;

typedef _Float16 f16x8 __attribute__((ext_vector_type(8)));
typedef float    f32x4 __attribute__((ext_vector_type(4)));

__device__ __forceinline__ void cvt_split(const float4& a0, const float4& a1,
                                          f16x8& h, f16x8& l) {
    float v[8] = {a0.x, a0.y, a0.z, a0.w, a1.x, a1.y, a1.z, a1.w};
#pragma unroll
    for (int j = 0; j < 8; ++j) {
        _Float16 hh = (_Float16)v[j];
        h[j] = hh;
        l[j] = (_Float16)(v[j] - (float)hh);
    }
}

// W (M x D fp32) -> frag-major hi/lo f16 + wsq. Thread = (unit u, k-octet o).
// Granule slot for (u, k=8o..8o+7), n-tile = 32 units:
//   T=u>>5, t=(u>>4)&1, c=u&15, s=o>>2, q=o&3
//   slot = T*512 + s*128 + t*64 + q*16 + c
// Main-loop read: tile_base(T*512) + s*128 + t*64 + lane. Sequential 1KB/instr.
// Also inits keys (u64 max) and per-sample-group completion counters.
__global__ __launch_bounds__(256) void prep_kernel(
        const float* __restrict__ w, f16x8* __restrict__ hG,
        f16x8* __restrict__ lG, float* __restrict__ wsq, int M,
        unsigned long long* __restrict__ keys, unsigned* __restrict__ cnt,
        int N, int nGroups) {
    int g = blockIdx.x * 256 + threadIdx.x;
    if (keys && g < N) keys[g] = ~0ull;
    if (cnt && g < nGroups) cnt[g] = 0u;
    if (g >= M * 16) return;
    int u = g >> 4, o = g & 15;
    const float4* wp = reinterpret_cast<const float4*>(w + (size_t)u * D + o * 8);
    float4 a0 = wp[0], a1 = wp[1];
    f16x8 h, l;
    cvt_split(a0, a1, h, l);
    float ss = 0.f;
    ss = fmaf(a0.x, a0.x, ss); ss = fmaf(a0.y, a0.y, ss);
    ss = fmaf(a0.z, a0.z, ss); ss = fmaf(a0.w, a0.w, ss);
    ss = fmaf(a1.x, a1.x, ss); ss = fmaf(a1.y, a1.y, ss);
    ss = fmaf(a1.z, a1.z, ss); ss = fmaf(a1.w, a1.w, ss);
#pragma unroll
    for (int m = 1; m < 16; m <<= 1) ss += __shfl_xor(ss, m, 64);
    if (o == 0) wsq[u] = ss;
    int slot = ((u >> 5) << 9) + ((o >> 2) << 7) + (((u >> 4) & 1) << 6)
             + ((o & 3) << 4) + (u & 15);
    hG[slot] = h;
    lG[slot] = l;
}

template <bool PARTIAL>
__global__ __launch_bounds__(256, 2) void som_main(
        const float* __restrict__ x, const f16x8* __restrict__ hG,
        const f16x8* __restrict__ lG, const float* __restrict__ wsq,
        const int* __restrict__ grid, int* __restrict__ out,
        unsigned long long* __restrict__ keys, unsigned* __restrict__ cnt,
        int unitGroups, int tilesQ, int tilesR, int N) {
    // Al (x-lo, k-steps 0..2), wave-private: wave wv owns albuf[wv*768..+768)
    // 48 KB total -> 3 blocks/CU (the whole point of this round).
    __shared__ f16x8 albuf[4 * 768];

    const int tid  = threadIdx.x;
    const int lane = tid & 63;
    const int wv   = tid >> 6;
    const int c    = lane & 15;   // frag col-class
    const int q    = lane >> 4;   // frag quad

    const int ug    = blockIdx.x % unitGroups;
    const int sg    = blockIdx.x / unitGroups;
    const int sWave = sg * 256 + wv * 64;   // this wave's 64 samples

    f16x8* myAl = &albuf[wv * 768];

    // ---- A-frags: 64 samples x K=128. Ah resident (64 VGPRs);
    // Al k-steps 0..2 -> LDS (12 granules), k-step 3 -> regs (Al3, 16 VGPRs).
    // A[m = lane&15][k = q*8 + j], m-tile i in 0..3, k-step s in 0..3.
    f16x8 Ah[16];
    f16x8 Al3[4];
#pragma unroll
    for (int i = 0; i < 4; ++i) {
        const float* xr = x + (size_t)(sWave + 16 * i + c) * D + q * 8;
#pragma unroll
        for (int s = 0; s < 4; ++s) {
            float4 a0 = *reinterpret_cast<const float4*>(xr + 32 * s);
            float4 a1 = *reinterpret_cast<const float4*>(xr + 32 * s + 4);
            f16x8 h, l;
            cvt_split(a0, a1, h, l);
            Ah[i * 4 + s] = h;
            if (s < 3) myAl[(i * 3 + s) * 64 + lane] = l;  // own slice: no barrier
            else       Al3[i] = l;
        }
    }

    float bestD[16];
    int   bestI[16];
#pragma unroll
    for (int sl = 0; sl < 16; ++sl) { bestD[sl] = FLT_MAX; bestI[sl] = 0; }

    const int tile0  = ug * tilesQ + (ug < tilesR ? ug : tilesR);
    const int tcount = tilesQ + (ug < tilesR ? 1 : 0);

    for (int tt = 0; tt < tcount; ++tt) {
        const int tile = tile0 + tt;
        const f16x8* hp = hG + ((size_t)tile << 9) + lane;
        const f16x8* lp = lG + ((size_t)tile << 9) + lane;

        // B tile into registers, round-6 source order (compiler sinks/batches
        // these optimally: bh reused by passes 1+2 -> loads amortized).
        f16x8 bh[8], bl[8];
#pragma unroll
        for (int s = 0; s < 4; ++s)
#pragma unroll
            for (int t = 0; t < 2; ++t)
                bh[s * 2 + t] = hp[s * 128 + t * 64];
#pragma unroll
        for (int s = 0; s < 4; ++s)
#pragma unroll
            for (int t = 0; t < 2; ++t)
                bl[s * 2 + t] = lp[s * 128 + t * 64];

        const int uTile = tile * 32;
        const float wq0 = wsq[uTile + c];
        const float wq1 = wsq[uTile + 16 + c];

        f32x4 acc[8];   // [i*2 + t]
#pragma unroll
        for (int f = 0; f < 8; ++f) acc[f] = (f32x4){0.f, 0.f, 0.f, 0.f};

        // pass 1: xh.wh
#pragma unroll
        for (int s = 0; s < 4; ++s)
#pragma unroll
            for (int i = 0; i < 4; ++i)
#pragma unroll
                for (int t = 0; t < 2; ++t)
                    acc[i * 2 + t] = __builtin_amdgcn_mfma_f32_16x16x32_f16(
                        Ah[i * 4 + s], bh[s * 2 + t], acc[i * 2 + t], 0, 0, 0);
        // pass 2: xl.wh (Al: s<3 from wave-private LDS, s==3 from regs)
#pragma unroll
        for (int s = 0; s < 4; ++s) {
            f16x8 al[4];
#pragma unroll
            for (int i = 0; i < 4; ++i)
                al[i] = (s < 3) ? myAl[(i * 3 + s) * 64 + lane] : Al3[i];
#pragma unroll
            for (int i = 0; i < 4; ++i)
#pragma unroll
                for (int t = 0; t < 2; ++t)
                    acc[i * 2 + t] = __builtin_amdgcn_mfma_f32_16x16x32_f16(
                        al[i], bh[s * 2 + t], acc[i * 2 + t], 0, 0, 0);
        }
        // pass 3: xh.wl
#pragma unroll
        for (int s = 0; s < 4; ++s)
#pragma unroll
            for (int i = 0; i < 4; ++i)
#pragma unroll
                for (int t = 0; t < 2; ++t)
                    acc[i * 2 + t] = __builtin_amdgcn_mfma_f32_16x16x32_f16(
                        Ah[i * 4 + s], bl[s * 2 + t], acc[i * 2 + t], 0, 0, 0);

        // ---- score + per-lane argmin. C layout: row m = q*4+r (+16i), col = c (+16t).
#pragma unroll
        for (int t = 0; t < 2; ++t) {
            const int n    = uTile + 16 * t + c;
            const float wq = t == 0 ? wq0 : wq1;
#pragma unroll
            for (int i = 0; i < 4; ++i) {
                f32x4 a = acc[i * 2 + t];
#pragma unroll
                for (int r = 0; r < 4; ++r) {
                    float score = fmaf(-2.f, a[r], wq);
                    int sl = i * 4 + r;
                    if (score < bestD[sl]) { bestD[sl] = score; bestI[sl] = n; }
                }
            }
        }
    }

    // ---- reduce over the 16 col-classes (xor within each 16-lane q-group) ----
#pragma unroll
    for (int sl = 0; sl < 16; ++sl) {
        float d   = bestD[sl];
        int   idx = bestI[sl];
#pragma unroll
        for (int m = 1; m < 16; m <<= 1) {
            float od = __shfl_xor(d, m, 64);
            int   oi = __shfl_xor(idx, m, 64);
            if (od < d || (od == d && oi < idx)) { d = od; idx = oi; }
        }
        if (c == 0) {
            const int sOut = sWave + 16 * (sl >> 2) + 4 * q + (sl & 3);
            if (PARTIAL) {
                unsigned ub = __float_as_uint(d);
                ub = (ub & 0x80000000u) ? ~ub : (ub | 0x80000000u);  // monotone map
                unsigned long long key = ((unsigned long long)ub << 32) | (unsigned)idx;
                atomicMin(&keys[sOut], key);
            } else {
                out[2 * sOut]     = grid[2 * idx];
                out[2 * sOut + 1] = grid[2 * idx + 1];
            }
        }
    }

    if (PARTIAL) {
        // Per-wave completion protocol (verified r10/r11): last of the
        // 4*unitGroups waves for this sample group writes the output.
        __threadfence();
        int old = 0;
        if (lane == 0) old = (int)atomicAdd(&cnt[sg], 1u);
        old = __shfl(old, 0, 64);
        if (old == 4 * unitGroups - 1) {
            __threadfence();
#pragma unroll
            for (int j = 0; j < 4; ++j) {
                const int s0 = sg * 256 + j * 64 + lane;
                unsigned long long k = atomicMin(&keys[s0], ~0ull);  // atomic read
                int idx = (int)(unsigned)(k & 0xFFFFFFFFull);
                out[2 * s0]     = grid[2 * idx];
                out[2 * s0 + 1] = grid[2 * idx + 1];
            }
        }
    }
}

extern "C" void kernel_launch(void* const* d_in, const int* in_sizes, int n_in,
                              void* d_out, int out_size, void* d_ws, size_t ws_size,
                              hipStream_t stream) {
    const float* x    = (const float*)d_in[0];
    const float* w    = (const float*)d_in[1];
    const int*   grid = (const int*)d_in[2];
    int* out = (int*)d_out;

    const int N = in_sizes[0] / D;   // 32768
    const int M = in_sizes[1] / D;   // 4096

    // ws layout: hG (1 MB) | lG (1 MB) | wsq (16 KB) | keys (N*8) | cnt
    const size_t hlBytes   = (size_t)M * D * 2;
    const size_t baseBytes = 2 * hlBytes + (size_t)M * 4;
    const int sampleGroups = N / 256;   // blocks of 4 waves x 64 samples
    const size_t needBytes = baseBytes + (size_t)N * 8 + (size_t)sampleGroups * 4;

    f16x8* hG  = (f16x8*)d_ws;
    f16x8* lG  = (f16x8*)((char*)d_ws + hlBytes);
    float* wsq = (float*)((char*)d_ws + 2 * hlBytes);
    unsigned long long* keys = (unsigned long long*)((char*)d_ws + baseBytes);
    unsigned* cnt = (unsigned*)((char*)d_ws + baseBytes + (size_t)N * 8);

    const int tiles = M / 32;           // 128 tiles of 32 units
    const int UG = (ws_size >= needBytes) ? 6 : 1;   // 768 blocks = 3/CU

    prep_kernel<<<(M * 16 + 255) / 256, 256, 0, stream>>>(
        w, hG, lG, wsq, M,
        UG > 1 ? keys : nullptr, UG > 1 ? cnt : nullptr, N, sampleGroups);

    const int tq = tiles / UG, trm = tiles % UG;
    if (UG > 1) {
        som_main<true><<<sampleGroups * UG, 256, 0, stream>>>(
            x, hG, lG, wsq, grid, out, keys, cnt, UG, tq, trm, N);
    } else {
        som_main<false><<<sampleGroups, 256, 0, stream>>>(
            x, hG, lG, wsq, grid, out, nullptr, nullptr, 1, tiles, 0, N);
    }
}